// Round 13
// baseline (209.617 us; speedup 1.0000x reference)
//
#include <hip/hip_runtime.h>

typedef unsigned short u16;
typedef unsigned int u32;
typedef __attribute__((ext_vector_type(8))) __bf16 bf16x8;
typedef __attribute__((ext_vector_type(4))) float f32x4;

union U8 {
  bf16x8 b;
  uint2 u2[2];
  uint4 u4;
  u32 w[4];
  u16 us[8];
};

__device__ __forceinline__ u16 f2bf(float f) {
  u32 x = __float_as_uint(f);
  x += 0x7FFFu + ((x >> 16) & 1u);
  return (u16)(x >> 16);
}
__device__ __forceinline__ float bf2f(u16 u) {
  return __uint_as_float(((u32)u) << 16);
}
// packed f32x2 -> bf16x2 (RNE), single instruction
__device__ __forceinline__ u32 cvtpk(float lo, float hi) {
  u32 r;
  asm("v_cvt_pk_bf16_f32 %0, %1, %2" : "=v"(r) : "v"(lo), "v"(hi));
  return r;
}

// async global->LDS, 16B per lane. LDS dest = wave-uniform base + lane*16.
#define GLOAD16(gp, lp)                                                          \
  __builtin_amdgcn_global_load_lds(                                              \
      (const __attribute__((address_space(1))) unsigned int*)(const void*)(gp),  \
      (__attribute__((address_space(3))) unsigned int*)(void*)(lp), 16, 0, 0)

// ---------------- f32 -> bf16 convert: x, W_qkv, W_out in one launch ----------------
__global__ void k_convert_all(const float* __restrict__ x, const float* __restrict__ wq,
                              const float* __restrict__ wo, u16* __restrict__ xb,
                              u16* __restrict__ wqb, u16* __restrict__ wob) {
  const int NX = 1048576, NQ = 786432, NO = 262144;  // float4 counts
  int idx = blockIdx.x * blockDim.x + threadIdx.x;
  int stride = gridDim.x * blockDim.x;
  for (int i = idx; i < NX + NQ + NO; i += stride) {
    const float4* s;
    ushort4* d;
    int k;
    if (i < NX) { s = (const float4*)x; d = (ushort4*)xb; k = i; }
    else if (i < NX + NQ) { s = (const float4*)wq; d = (ushort4*)wqb; k = i - NX; }
    else { s = (const float4*)wo; d = (ushort4*)wob; k = i - NX - NQ; }
    float4 v = s[k];
    ushort4 o;
    o.x = f2bf(v.x); o.y = f2bf(v.y); o.z = f2bf(v.z); o.w = f2bf(v.w);
    d[k] = o;
  }
}

// ---------------- GEMM (qkv): 128x128 tile, BK=64, gload_lds + XOR swizzle ----------------
// Q,K scatter [b][h][n][d]; V written transposed [b][h][d][n] (uint2/fragment).
__global__ __launch_bounds__(256) void k_gemm_qkv(const u16* __restrict__ A,
                                                  const u16* __restrict__ Bm,
                                                  const float* __restrict__ bias,
                                                  u16* __restrict__ Qo, u16* __restrict__ Ko,
                                                  u16* __restrict__ Vo) {
  const int K = 1024;
  __shared__ u16 Al[128 * 64];
  __shared__ u16 Bl[128 * 64];
  const int t = threadIdx.x;
  const int lane = t & 63, wid = t >> 6;
  const int g = lane >> 4, i16 = lane & 15;
  const int wm = wid >> 1, wn = wid & 1;
  const int bm = blockIdx.y, bn = blockIdx.x;

  f32x4 zero = {0.f, 0.f, 0.f, 0.f};
  f32x4 acc[4][4];
#pragma unroll
  for (int mi = 0; mi < 4; ++mi)
#pragma unroll
    for (int ni = 0; ni < 4; ++ni) acc[mi][ni] = zero;

  int srow[4], sgc[4];
#pragma unroll
  for (int i = 0; i < 4; ++i) {
    int ch = wid * 256 + i * 64 + lane;
    int r = ch >> 3, cs = ch & 7;
    srow[i] = r;
    sgc[i] = cs ^ (r & 7);
  }

  for (int k0 = 0; k0 < K; k0 += 64) {
    __syncthreads();
#pragma unroll
    for (int i = 0; i < 4; ++i) {
      const u16* ga = A + (size_t)(bm * 128 + srow[i]) * K + k0 + sgc[i] * 8;
      const u16* gb = Bm + (size_t)(bn * 128 + srow[i]) * K + k0 + sgc[i] * 8;
      GLOAD16(ga, Al + (size_t)(wid * 256 + i * 64) * 8);
      GLOAD16(gb, Bl + (size_t)(wid * 256 + i * 64) * 8);
    }
    __syncthreads();

#pragma unroll
    for (int kk = 0; kk < 2; ++kk) {
      U8 af[4], bfr[4];
#pragma unroll
      for (int mi = 0; mi < 4; ++mi) {
        int row = wm * 64 + mi * 16 + i16;
        int ch = (g + 4 * kk) ^ (row & 7);
        af[mi].u4 = *(const uint4*)(Al + row * 64 + ch * 8);
      }
#pragma unroll
      for (int ni = 0; ni < 4; ++ni) {
        int row = wn * 64 + ni * 16 + i16;
        int ch = (g + 4 * kk) ^ (row & 7);
        bfr[ni].u4 = *(const uint4*)(Bl + row * 64 + ch * 8);
      }
#pragma unroll
      for (int mi = 0; mi < 4; ++mi)
#pragma unroll
        for (int ni = 0; ni < 4; ++ni)
          acc[mi][ni] = __builtin_amdgcn_mfma_f32_16x16x32_bf16(af[mi].b, bfr[ni].b,
                                                                acc[mi][ni], 0, 0, 0);
    }
  }

#pragma unroll
  for (int mi = 0; mi < 4; ++mi) {
#pragma unroll
    for (int ni = 0; ni < 4; ++ni) {
      int col = bn * 128 + wn * 64 + ni * 16 + i16;
      int row0 = bm * 128 + wm * 64 + mi * 16 + 4 * g;
      float bia = bias[col];
      int tt = col >> 10;
      int h = (col >> 6) & 15;
      int d = col & 63;
      int b = row0 >> 9;
      int n0 = row0 & 511;  // n0..n0+3 stay within this (b,h)
      if (tt < 2) {
        u16* dst = (tt == 0) ? Qo : Ko;
#pragma unroll
        for (int j = 0; j < 4; ++j)
          dst[((size_t)(b * 16 + h) * 512 + n0 + j) * 64 + d] = f2bf(acc[mi][ni][j] + bia);
      } else {
        uint2 w;
        w.x = cvtpk(acc[mi][ni][0] + bia, acc[mi][ni][1] + bia);
        w.y = cvtpk(acc[mi][ni][2] + bia, acc[mi][ni][3] + bia);
        *(uint2*)(Vo + ((size_t)(b * 16 + h) * 64 + d) * 512 + n0) = w;
      }
    }
  }
}

// ---------------- GEMM (out): 128x128 tile, f32 C + bias ----------------
__global__ __launch_bounds__(256) void k_gemm_out(const u16* __restrict__ A,
                                                  const u16* __restrict__ Bm,
                                                  const float* __restrict__ bias,
                                                  float* __restrict__ Co) {
  const int K = 1024;
  __shared__ u16 Al[128 * 64];
  __shared__ u16 Bl[128 * 64];
  const int t = threadIdx.x;
  const int lane = t & 63, wid = t >> 6;
  const int g = lane >> 4, i16 = lane & 15;
  const int wm = wid >> 1, wn = wid & 1;
  const int bm = blockIdx.y, bn = blockIdx.x;

  f32x4 zero = {0.f, 0.f, 0.f, 0.f};
  f32x4 acc[4][4];
#pragma unroll
  for (int mi = 0; mi < 4; ++mi)
#pragma unroll
    for (int ni = 0; ni < 4; ++ni) acc[mi][ni] = zero;

  int srow[4], sgc[4];
#pragma unroll
  for (int i = 0; i < 4; ++i) {
    int ch = wid * 256 + i * 64 + lane;
    int r = ch >> 3, cs = ch & 7;
    srow[i] = r;
    sgc[i] = cs ^ (r & 7);
  }

  for (int k0 = 0; k0 < K; k0 += 64) {
    __syncthreads();
#pragma unroll
    for (int i = 0; i < 4; ++i) {
      GLOAD16(A + (size_t)(bm * 128 + srow[i]) * K + k0 + sgc[i] * 8,
              Al + (size_t)(wid * 256 + i * 64) * 8);
      GLOAD16(Bm + (size_t)(bn * 128 + srow[i]) * K + k0 + sgc[i] * 8,
              Bl + (size_t)(wid * 256 + i * 64) * 8);
    }
    __syncthreads();

#pragma unroll
    for (int kk = 0; kk < 2; ++kk) {
      U8 af[4], bfr[4];
#pragma unroll
      for (int mi = 0; mi < 4; ++mi) {
        int row = wm * 64 + mi * 16 + i16;
        int ch = (g + 4 * kk) ^ (row & 7);
        af[mi].u4 = *(const uint4*)(Al + row * 64 + ch * 8);
      }
#pragma unroll
      for (int ni = 0; ni < 4; ++ni) {
        int row = wn * 64 + ni * 16 + i16;
        int ch = (g + 4 * kk) ^ (row & 7);
        bfr[ni].u4 = *(const uint4*)(Bl + row * 64 + ch * 8);
      }
#pragma unroll
      for (int mi = 0; mi < 4; ++mi)
#pragma unroll
        for (int ni = 0; ni < 4; ++ni)
          acc[mi][ni] = __builtin_amdgcn_mfma_f32_16x16x32_bf16(af[mi].b, bfr[ni].b,
                                                                acc[mi][ni], 0, 0, 0);
    }
  }

#pragma unroll
  for (int mi = 0; mi < 4; ++mi) {
#pragma unroll
    for (int ni = 0; ni < 4; ++ni) {
      int col = bn * 128 + wn * 64 + ni * 16 + i16;
      int row0 = bm * 128 + wm * 64 + mi * 16 + 4 * g;
      float bia = bias[col];
#pragma unroll
      for (int j = 0; j < 4; ++j)
        Co[(size_t)(row0 + j) * 1024 + col] = acc[mi][ni][j] + bia;
    }
  }
}

// ---------------- FUSED attention + rel projection ----------------
// grid (nt=32, b=8) = 256 blocks x 1024 threads (16 waves; wave wid = head h).
// Per m-tile (64 cols): all waves cooperatively project the rel patch for ALL
// 16 heads (each thread reads ONE rel_bias row of 32 f32 ONCE -> 16 h-dots ->
// LDS patch in consumer fragment order, double-buffered); then each wave loads
// its own head's K / Vt tile DIRECTLY to registers (K regs reused for V) and
// runs QK^T -> +rel -> online softmax -> PV. One barrier per tile.
// Eliminates the 64MB rel materialize + 64MB re-read; K/Vt re-reads (32x per b)
// are L3-served (16MB unique << 256MB L3).
__global__ __launch_bounds__(1024) void k_attn_rel(
    const u16* __restrict__ Q, const u16* __restrict__ Kb, const u16* __restrict__ Vtb,
    const float* __restrict__ rb, const float* __restrict__ Wr, const float* __restrict__ br,
    u16* __restrict__ Out) {
  __shared__ u16 relP[2][16 * 1024];  // [buf][h*1024 + c*256 + lane*4 + j]  (64 KB)
  __shared__ u16 Pl[16][16 * 68];     // per-wave P round-trip               (34 KB)

  const int nt = blockIdx.x, b = blockIdx.y;
  const int t = threadIdx.x;
  const int lane = t & 63, wid = t >> 6;  // wid = h
  const int g = lane >> 4, i16 = lane & 15;
  const size_t bh = (size_t)(b * 16 + wid);

  // ---- rel-producer indexing (one (n,m) point per thread, all 16 h) ----
  const int pr_i16 = t & 15, pr_j = (t >> 4) & 3, pr_gg = (t >> 6) & 3, pr_c = t >> 8;
  const int pr_n = nt * 16 + 4 * pr_gg + pr_j;
  const int pr_moff = pr_c * 16 + pr_i16;
  const float* pr_base = rb + ((size_t)(b * 512 + pr_n) * 512 + pr_moff) * 32;
  const int pr_sto = pr_c * 256 + (pr_gg * 16 + pr_i16) * 4 + pr_j;

#define REL_A(bufi, iti)                                                              \
  do {                                                                                \
    const float4* rp = (const float4*)(pr_base + (size_t)(iti) * 2048);               \
    float4 r4[8];                                                                     \
    _Pragma("unroll") for (int q = 0; q < 8; ++q) r4[q] = rp[q];                      \
    _Pragma("unroll") for (int h = 0; h < 16; ++h) {                                  \
      float a = br[h];                                                                \
      const float* w = Wr + h * 32;                                                   \
      _Pragma("unroll") for (int q = 0; q < 8; ++q) {                                 \
        a += r4[q].x * w[4 * q] + r4[q].y * w[4 * q + 1] + r4[q].z * w[4 * q + 2] +   \
             r4[q].w * w[4 * q + 3];                                                  \
      }                                                                               \
      relP[bufi][h * 1024 + pr_sto] = f2bf(a);                                        \
    }                                                                                 \
  } while (0)

  // ---- per-wave Q fragments (16 q-rows for head wid) ----
  const u16* Qg = Q + (bh * 512 + nt * 16 + i16) * 64;
  U8 qf[2];
  qf[0].u4 = *(const uint4*)(Qg + 8 * g);
  qf[1].u4 = *(const uint4*)(Qg + 8 * g + 32);

  float m_run[4], l_run[4];
  f32x4 zero = {0.f, 0.f, 0.f, 0.f};
  f32x4 acc[4];
#pragma unroll
  for (int c = 0; c < 4; ++c) acc[c] = zero;
#pragma unroll
  for (int j = 0; j < 4; ++j) { m_run[j] = -1e30f; l_run[j] = 0.f; }

  const u16* Kg0 = Kb + bh * 32768;   // [m][d]
  const u16* Vg0 = Vtb + bh * 32768;  // [d][n]

  REL_A(0, 0);
  __syncthreads();

  for (int it = 0; it < 8; ++it) {
    const int buf = it & 1;
    const int m0 = it * 64;

    if (it < 7) REL_A(buf ^ 1, it + 1);

    // K tile -> regs, QK^T
    U8 tile[4][2];
#pragma unroll
    for (int c = 0; c < 4; ++c)
#pragma unroll
      for (int kk = 0; kk < 2; ++kk)
        tile[c][kk].u4 =
            *(const uint4*)(Kg0 + (size_t)(m0 + c * 16 + i16) * 64 + 8 * g + 32 * kk);

    f32x4 s[4];
#pragma unroll
    for (int c = 0; c < 4; ++c) s[c] = zero;
    __builtin_amdgcn_s_setprio(1);
#pragma unroll
    for (int c = 0; c < 4; ++c)
#pragma unroll
      for (int kk = 0; kk < 2; ++kk)
        s[c] = __builtin_amdgcn_mfma_f32_16x16x32_bf16(qf[kk].b, tile[c][kk].b, s[c], 0, 0, 0);
    __builtin_amdgcn_s_setprio(0);

    // + rel (from LDS patch, this head's region)
#pragma unroll
    for (int c = 0; c < 4; ++c) {
      uint2 rr = *(const uint2*)(&relP[buf][wid * 1024 + c * 256 + lane * 4]);
      const u16* rc = (const u16*)&rr;
#pragma unroll
      for (int j = 0; j < 4; ++j) s[c][j] = s[c][j] * 0.125f + bf2f(rc[j]);
    }

    // online softmax (rows live across the 16 lanes sharing g)
    float fac[4];
#pragma unroll
    for (int j = 0; j < 4; ++j) {
      float pm = fmaxf(fmaxf(s[0][j], s[1][j]), fmaxf(s[2][j], s[3][j]));
      pm = fmaxf(pm, __shfl_xor(pm, 1));
      pm = fmaxf(pm, __shfl_xor(pm, 2));
      pm = fmaxf(pm, __shfl_xor(pm, 4));
      pm = fmaxf(pm, __shfl_xor(pm, 8));
      float mnew = fmaxf(m_run[j], pm);
      fac[j] = __expf(m_run[j] - mnew);
      m_run[j] = mnew;
    }
#pragma unroll
    for (int c = 0; c < 4; ++c)
#pragma unroll
      for (int j = 0; j < 4; ++j) s[c][j] = __expf(s[c][j] - m_run[j]);
#pragma unroll
    for (int j = 0; j < 4; ++j) {
      float rs = s[0][j] + s[1][j] + s[2][j] + s[3][j];
      rs += __shfl_xor(rs, 1);
      rs += __shfl_xor(rs, 2);
      rs += __shfl_xor(rs, 4);
      rs += __shfl_xor(rs, 8);
      l_run[j] = l_run[j] * fac[j] + rs;
    }
#pragma unroll
    for (int c = 0; c < 4; ++c)
#pragma unroll
      for (int j = 0; j < 4; ++j) acc[c][j] *= fac[j];

    // P -> per-wave LDS (wave-private; lgkmcnt orders write->read)
    u16* Pw = Pl[wid];
#pragma unroll
    for (int c = 0; c < 4; ++c)
#pragma unroll
      for (int j = 0; j < 4; ++j)
        Pw[(4 * g + j) * 68 + c * 16 + i16] = f2bf(s[c][j]);

    U8 pf[2];
#pragma unroll
    for (int kk = 0; kk < 2; ++kk) {
      const u16* p = Pl[wid] + i16 * 68 + 8 * g + 32 * kk;
      pf[kk].u2[0] = *(const uint2*)p;
      pf[kk].u2[1] = *(const uint2*)(p + 4);
    }

    // V tile -> regs (reuse `tile`), PV
#pragma unroll
    for (int c = 0; c < 4; ++c)
#pragma unroll
      for (int kk = 0; kk < 2; ++kk)
        tile[c][kk].u4 =
            *(const uint4*)(Vg0 + (size_t)(c * 16 + i16) * 512 + m0 + 8 * g + 32 * kk);

    __builtin_amdgcn_s_setprio(1);
#pragma unroll
    for (int c = 0; c < 4; ++c)
#pragma unroll
      for (int kk = 0; kk < 2; ++kk)
        acc[c] = __builtin_amdgcn_mfma_f32_16x16x32_bf16(pf[kk].b, tile[c][kk].b, acc[c], 0, 0, 0);
    __builtin_amdgcn_s_setprio(0);

    __syncthreads();  // relP[buf^1] ready for next iter; protects dbuf reuse
  }
#undef REL_A

  // epilogue: normalize, write bf16 [b][n][h*64+d]
#pragma unroll
  for (int c = 0; c < 4; ++c) {
#pragma unroll
    for (int j = 0; j < 4; ++j) {
      int n = nt * 16 + 4 * g + j;
      float v = acc[c][j] / l_run[j];
      Out[((size_t)b * 512 + n) * 1024 + wid * 64 + c * 16 + i16] = f2bf(v);
    }
  }
}

// ---------------- launcher ----------------
extern "C" void kernel_launch(void* const* d_in, const int* in_sizes, int n_in,
                              void* d_out, int out_size, void* d_ws, size_t ws_size,
                              hipStream_t stream) {
  const float* x = (const float*)d_in[0];
  const float* rel_bias = (const float*)d_in[1];
  const float* W_qkv = (const float*)d_in[2];
  const float* b_qkv = (const float*)d_in[3];
  const float* W_rel = (const float*)d_in[4];
  const float* b_rel = (const float*)d_in[5];
  const float* W_out = (const float*)d_in[6];
  const float* b_out = (const float*)d_in[7];
  float* out = (float*)d_out;

  char* ws = (char*)d_ws;
  u16* x_bf    = (u16*)(ws);               //  8 MB  (4096x1024)
  u16* wqkv_bf = (u16*)(ws + 8388608);     //  6 MB  (3072x1024)
  u16* wout_bf = (u16*)(ws + 14680064);    //  2 MB  (1024x1024)
  u16* Qw      = (u16*)(ws + 16777216);    //  8 MB  [b][h][n][d]
  u16* Kw      = (u16*)(ws + 25165824);    //  8 MB  [b][h][n][d]
  u16* Vt      = (u16*)(ws + 33554432);    //  8 MB  [b][h][d][n] (written by qkv gemm)
  u16* attno   = (u16*)(ws + 109051904);   //  8 MB  (4096x1024)

  k_convert_all<<<2048, 256, 0, stream>>>(x, W_qkv, W_out, x_bf, wqkv_bf, wout_bf);

  k_gemm_qkv<<<dim3(24, 32), 256, 0, stream>>>(x_bf, wqkv_bf, b_qkv, Qw, Kw, Vt);

  k_attn_rel<<<dim3(32, 8), 1024, 0, stream>>>(Qw, Kw, Vt, rel_bias, W_rel, b_rel, attno);

  k_gemm_out<<<dim3(8, 32), 256, 0, stream>>>(attno, wout_bf, b_out, out);
}

// Round 14
// 190.656 us; speedup vs baseline: 1.0995x; 1.0995x over previous
//
#include <hip/hip_runtime.h>

typedef unsigned short u16;
typedef unsigned int u32;
typedef __attribute__((ext_vector_type(8))) __bf16 bf16x8;
typedef __attribute__((ext_vector_type(4))) float f32x4;

union U8 {
  bf16x8 b;
  uint2 u2[2];
  uint4 u4;
  u32 w[4];
  u16 us[8];
};

__device__ __forceinline__ u16 f2bf(float f) {
  u32 x = __float_as_uint(f);
  x += 0x7FFFu + ((x >> 16) & 1u);
  return (u16)(x >> 16);
}
__device__ __forceinline__ float bf2f(u16 u) {
  return __uint_as_float(((u32)u) << 16);
}
// packed f32x2 -> bf16x2 (RNE), single instruction
__device__ __forceinline__ u32 cvtpk(float lo, float hi) {
  u32 r;
  asm("v_cvt_pk_bf16_f32 %0, %1, %2" : "=v"(r) : "v"(lo), "v"(hi));
  return r;
}

// async global->LDS, 16B per lane. LDS dest = wave-uniform base + lane*16.
#define GLOAD16(gp, lp)                                                          \
  __builtin_amdgcn_global_load_lds(                                              \
      (const __attribute__((address_space(1))) unsigned int*)(const void*)(gp),  \
      (__attribute__((address_space(3))) unsigned int*)(void*)(lp), 16, 0, 0)

// ---------------- f32 -> bf16 convert: x, W_qkv, W_out in one launch ----------------
__global__ void k_convert_all(const float* __restrict__ x, const float* __restrict__ wq,
                              const float* __restrict__ wo, u16* __restrict__ xb,
                              u16* __restrict__ wqb, u16* __restrict__ wob) {
  const int NX = 1048576, NQ = 786432, NO = 262144;  // float4 counts
  int idx = blockIdx.x * blockDim.x + threadIdx.x;
  int stride = gridDim.x * blockDim.x;
  for (int i = idx; i < NX + NQ + NO; i += stride) {
    const float4* s;
    ushort4* d;
    int k;
    if (i < NX) { s = (const float4*)x; d = (ushort4*)xb; k = i; }
    else if (i < NX + NQ) { s = (const float4*)wq; d = (ushort4*)wqb; k = i - NX; }
    else { s = (const float4*)wo; d = (ushort4*)wob; k = i - NX - NQ; }
    float4 v = s[k];
    ushort4 o;
    o.x = f2bf(v.x); o.y = f2bf(v.y); o.z = f2bf(v.z); o.w = f2bf(v.w);
    d[k] = o;
  }
}

// ---------------- rel projection v3: unit-stride global loads via LDS stage ----------------
// R7's pattern read 128B/thread at lane-stride 128B -> 64 line-requests per
// global_load_dwordx4 (VM request-rate bound, ~63us vs 43us HBM floor).
// v3: block stages its 256 rows (32KB) as 4 contiguous 8KB chunks with
// unit-stride lane addressing (8 lines/inst), XOR-swizzled into LDS
// (slot = row*8 + (q ^ (row&7)) -> balanced 8-phase b128, no excess conflict),
// then each thread reads its own row back and runs the proven R7 dot+store.
// out[tile(b,h,nt,mt)*1024 + c*256 + (g*16+i16)*4 + j]
//   n = nt*16 + 4g + j, m = mt*64 + c*16 + i16.
__global__ __launch_bounds__(256) void k_rel(const float* __restrict__ rb,
                                             const float* __restrict__ Wr,
                                             const float* __restrict__ br,
                                             u16* __restrict__ out) {
  __shared__ float4 Ls[256 * 8];  // 32 KB
  const int t = threadIdx.x;
  const int i16 = t & 15, j = (t >> 4) & 3, c = t >> 6;
  const int mt = blockIdx.x, ntg = blockIdx.y, b = blockIdx.z;
  const int nt = ntg >> 2, g = ntg & 3;

  // stage: 4 chunks (cn = n-offset j'), each 64 rows x 128 B, unit-stride
#pragma unroll
  for (int cn = 0; cn < 4; ++cn) {
    const int n = nt * 16 + 4 * g + cn;
    const float4* src = (const float4*)(rb + ((size_t)(b * 512 + n) * 512 + mt * 64) * 32);
#pragma unroll
    for (int k = 0; k < 2; ++k) {
      int f = k * 256 + t;  // float4 index within chunk (0..511)
      int rr = f >> 3, q = f & 7;
      int row = cn * 64 + rr;
      Ls[row * 8 + (q ^ (row & 7))] = src[f];
    }
  }
  __syncthreads();

  // my row: n-chunk j, m-offset c*16+i16
  const int myrow = j * 64 + c * 16 + i16;
  float4 r4[8];
#pragma unroll
  for (int q = 0; q < 8; ++q) r4[q] = Ls[myrow * 8 + (q ^ (myrow & 7))];

  const size_t obase =
      (((size_t)(b * 16) * 32 + nt) * 8 + mt) * 1024 + c * 256 + (g * 16 + i16) * 4 + j;
#pragma unroll
  for (int h = 0; h < 16; ++h) {
    float acc = br[h];
    const float* w = Wr + h * 32;
#pragma unroll
    for (int q = 0; q < 8; ++q) {
      acc += r4[q].x * w[4 * q + 0] + r4[q].y * w[4 * q + 1] +
             r4[q].z * w[4 * q + 2] + r4[q].w * w[4 * q + 3];
    }
    out[obase + (size_t)h * 262144] = f2bf(acc);
  }
}

// ---------------- GEMM (qkv): 128x128 tile, BK=64, gload_lds + XOR swizzle ----------------
// Q,K scatter [b][h][n][d]; V written transposed [b][h][d][n] (uint2/fragment).
__global__ __launch_bounds__(256) void k_gemm_qkv(const u16* __restrict__ A,
                                                  const u16* __restrict__ Bm,
                                                  const float* __restrict__ bias,
                                                  u16* __restrict__ Qo, u16* __restrict__ Ko,
                                                  u16* __restrict__ Vo) {
  const int K = 1024;
  __shared__ u16 Al[128 * 64];
  __shared__ u16 Bl[128 * 64];
  const int t = threadIdx.x;
  const int lane = t & 63, wid = t >> 6;
  const int g = lane >> 4, i16 = lane & 15;
  const int wm = wid >> 1, wn = wid & 1;
  const int bm = blockIdx.y, bn = blockIdx.x;

  f32x4 zero = {0.f, 0.f, 0.f, 0.f};
  f32x4 acc[4][4];
#pragma unroll
  for (int mi = 0; mi < 4; ++mi)
#pragma unroll
    for (int ni = 0; ni < 4; ++ni) acc[mi][ni] = zero;

  int srow[4], sgc[4];
#pragma unroll
  for (int i = 0; i < 4; ++i) {
    int ch = wid * 256 + i * 64 + lane;
    int r = ch >> 3, cs = ch & 7;
    srow[i] = r;
    sgc[i] = cs ^ (r & 7);
  }

  for (int k0 = 0; k0 < K; k0 += 64) {
    __syncthreads();
#pragma unroll
    for (int i = 0; i < 4; ++i) {
      const u16* ga = A + (size_t)(bm * 128 + srow[i]) * K + k0 + sgc[i] * 8;
      const u16* gb = Bm + (size_t)(bn * 128 + srow[i]) * K + k0 + sgc[i] * 8;
      GLOAD16(ga, Al + (size_t)(wid * 256 + i * 64) * 8);
      GLOAD16(gb, Bl + (size_t)(wid * 256 + i * 64) * 8);
    }
    __syncthreads();

#pragma unroll
    for (int kk = 0; kk < 2; ++kk) {
      U8 af[4], bfr[4];
#pragma unroll
      for (int mi = 0; mi < 4; ++mi) {
        int row = wm * 64 + mi * 16 + i16;
        int ch = (g + 4 * kk) ^ (row & 7);
        af[mi].u4 = *(const uint4*)(Al + row * 64 + ch * 8);
      }
#pragma unroll
      for (int ni = 0; ni < 4; ++ni) {
        int row = wn * 64 + ni * 16 + i16;
        int ch = (g + 4 * kk) ^ (row & 7);
        bfr[ni].u4 = *(const uint4*)(Bl + row * 64 + ch * 8);
      }
#pragma unroll
      for (int mi = 0; mi < 4; ++mi)
#pragma unroll
        for (int ni = 0; ni < 4; ++ni)
          acc[mi][ni] = __builtin_amdgcn_mfma_f32_16x16x32_bf16(af[mi].b, bfr[ni].b,
                                                                acc[mi][ni], 0, 0, 0);
    }
  }

#pragma unroll
  for (int mi = 0; mi < 4; ++mi) {
#pragma unroll
    for (int ni = 0; ni < 4; ++ni) {
      int col = bn * 128 + wn * 64 + ni * 16 + i16;
      int row0 = bm * 128 + wm * 64 + mi * 16 + 4 * g;
      float bia = bias[col];
      int tt = col >> 10;
      int h = (col >> 6) & 15;
      int d = col & 63;
      int b = row0 >> 9;
      int n0 = row0 & 511;  // n0..n0+3 stay within this (b,h)
      if (tt < 2) {
        u16* dst = (tt == 0) ? Qo : Ko;
#pragma unroll
        for (int j = 0; j < 4; ++j)
          dst[((size_t)(b * 16 + h) * 512 + n0 + j) * 64 + d] = f2bf(acc[mi][ni][j] + bia);
      } else {
        uint2 w;
        w.x = cvtpk(acc[mi][ni][0] + bia, acc[mi][ni][1] + bia);
        w.y = cvtpk(acc[mi][ni][2] + bia, acc[mi][ni][3] + bia);
        *(uint2*)(Vo + ((size_t)(b * 16 + h) * 64 + d) * 512 + n0) = w;
      }
    }
  }
}

// ---------------- GEMM (out): 128x128 tile, f32 C + bias ----------------
__global__ __launch_bounds__(256) void k_gemm_out(const u16* __restrict__ A,
                                                  const u16* __restrict__ Bm,
                                                  const float* __restrict__ bias,
                                                  float* __restrict__ Co) {
  const int K = 1024;
  __shared__ u16 Al[128 * 64];
  __shared__ u16 Bl[128 * 64];
  const int t = threadIdx.x;
  const int lane = t & 63, wid = t >> 6;
  const int g = lane >> 4, i16 = lane & 15;
  const int wm = wid >> 1, wn = wid & 1;
  const int bm = blockIdx.y, bn = blockIdx.x;

  f32x4 zero = {0.f, 0.f, 0.f, 0.f};
  f32x4 acc[4][4];
#pragma unroll
  for (int mi = 0; mi < 4; ++mi)
#pragma unroll
    for (int ni = 0; ni < 4; ++ni) acc[mi][ni] = zero;

  int srow[4], sgc[4];
#pragma unroll
  for (int i = 0; i < 4; ++i) {
    int ch = wid * 256 + i * 64 + lane;
    int r = ch >> 3, cs = ch & 7;
    srow[i] = r;
    sgc[i] = cs ^ (r & 7);
  }

  for (int k0 = 0; k0 < K; k0 += 64) {
    __syncthreads();
#pragma unroll
    for (int i = 0; i < 4; ++i) {
      GLOAD16(A + (size_t)(bm * 128 + srow[i]) * K + k0 + sgc[i] * 8,
              Al + (size_t)(wid * 256 + i * 64) * 8);
      GLOAD16(Bm + (size_t)(bn * 128 + srow[i]) * K + k0 + sgc[i] * 8,
              Bl + (size_t)(wid * 256 + i * 64) * 8);
    }
    __syncthreads();

#pragma unroll
    for (int kk = 0; kk < 2; ++kk) {
      U8 af[4], bfr[4];
#pragma unroll
      for (int mi = 0; mi < 4; ++mi) {
        int row = wm * 64 + mi * 16 + i16;
        int ch = (g + 4 * kk) ^ (row & 7);
        af[mi].u4 = *(const uint4*)(Al + row * 64 + ch * 8);
      }
#pragma unroll
      for (int ni = 0; ni < 4; ++ni) {
        int row = wn * 64 + ni * 16 + i16;
        int ch = (g + 4 * kk) ^ (row & 7);
        bfr[ni].u4 = *(const uint4*)(Bl + row * 64 + ch * 8);
      }
#pragma unroll
      for (int mi = 0; mi < 4; ++mi)
#pragma unroll
        for (int ni = 0; ni < 4; ++ni)
          acc[mi][ni] = __builtin_amdgcn_mfma_f32_16x16x32_bf16(af[mi].b, bfr[ni].b,
                                                                acc[mi][ni], 0, 0, 0);
    }
  }

#pragma unroll
  for (int mi = 0; mi < 4; ++mi) {
#pragma unroll
    for (int ni = 0; ni < 4; ++ni) {
      int col = bn * 128 + wn * 64 + ni * 16 + i16;
      int row0 = bm * 128 + wm * 64 + mi * 16 + 4 * g;
      float bia = bias[col];
#pragma unroll
      for (int j = 0; j < 4; ++j)
        Co[(size_t)(row0 + j) * 1024 + col] = acc[mi][ni][j] + bia;
    }
  }
}

// ---------------- fused attention: softmax(Q K^T * scale + rel) V ----------------
// grid (qt=8, h=16, b=8), 256 threads = 4 waves, each wave owns 16 q-rows.
// K/Vt double-buffered via global_load_lds, prefetch issued before compute.
// rel read as 4x uint2 per thread per tile (dense fragment-ordered layout).
// Mid-loop barrier removed (R12): Pl is wave-private, lgkmcnt orders it.
__global__ __launch_bounds__(256) void k_attn(const u16* __restrict__ Q,
                                              const u16* __restrict__ Kb,
                                              const u16* __restrict__ Vtb,
                                              const u16* __restrict__ Rel,
                                              u16* __restrict__ Out) {
  __shared__ u16 Kl[2][64 * 64];
  __shared__ u16 Vl[2][64 * 64];
  __shared__ u16 Pl[4][16 * 68];

  const int qt = blockIdx.x, h = blockIdx.y, b = blockIdx.z;
  const int t = threadIdx.x, lane = t & 63, wid = t >> 6;
  const int g = lane >> 4, i16 = lane & 15;
  const size_t bh = (size_t)(b * 16 + h);

  // Q fragments (held in registers for entire kernel)
  const u16* Qg = Q + (bh * 512 + qt * 64 + wid * 16 + i16) * 64;
  U8 qf[2];
  qf[0].u4 = *(const uint4*)(Qg + 8 * g);
  qf[1].u4 = *(const uint4*)(Qg + 8 * g + 32);

  float m_run[4], l_run[4];
  f32x4 zero = {0.f, 0.f, 0.f, 0.f};
  f32x4 acc[4];
#pragma unroll
  for (int c = 0; c < 4; ++c) acc[c] = zero;
#pragma unroll
  for (int j = 0; j < 4; ++j) { m_run[j] = -1e30f; l_run[j] = 0.f; }

  int srow[2], sgc[2];
#pragma unroll
  for (int i = 0; i < 2; ++i) {
    int ch = wid * 128 + i * 64 + lane;
    int r = ch >> 3, cs = ch & 7;
    srow[i] = r;
    sgc[i] = cs ^ (r & 7);
  }

  const u16* Kg0 = Kb + bh * 512 * 64;
  const u16* Vg0 = Vtb + bh * 64 * 512;
  // fragment-ordered rel: tile(b,h, nt=qt*4+wid, mt=it)*1024 + c*256 + lane*4 + j
  const u16* Rg = Rel + ((bh * 32 + qt * 4 + wid) * 8) * 1024 + lane * 4;

#define STAGE(buf, m0)                                                                  \
  do {                                                                                  \
    _Pragma("unroll") for (int i = 0; i < 2; ++i) {                                     \
      GLOAD16(Kg0 + (size_t)((m0) + srow[i]) * 64 + sgc[i] * 8,                         \
              &Kl[buf][(size_t)(wid * 128 + i * 64) * 8]);                              \
      GLOAD16(Vg0 + (size_t)srow[i] * 512 + (m0) + sgc[i] * 8,                          \
              &Vl[buf][(size_t)(wid * 128 + i * 64) * 8]);                              \
    }                                                                                   \
  } while (0)

  STAGE(0, 0);
  __syncthreads();

  for (int it = 0; it < 8; ++it) {
    const int buf = it & 1;
    if (it < 7) STAGE(buf ^ 1, it * 64 + 64);

    // rel fragments: 4 x uint2 (dense per wave), in flight under QK^T
    uint2 rl[4];
#pragma unroll
    for (int c = 0; c < 4; ++c) rl[c] = *(const uint2*)(Rg + it * 1024 + c * 256);

    // S = Q K^T  (per wave: 16 x 64)
    f32x4 s[4];
#pragma unroll
    for (int c = 0; c < 4; ++c) s[c] = zero;
    __builtin_amdgcn_s_setprio(1);
#pragma unroll
    for (int c = 0; c < 4; ++c) {
#pragma unroll
      for (int kk = 0; kk < 2; ++kk) {
        int row = c * 16 + i16;
        int ch = (g + 4 * kk) ^ (row & 7);
        U8 kf;
        kf.u4 = *(const uint4*)(&Kl[buf][row * 64 + ch * 8]);
        s[c] = __builtin_amdgcn_mfma_f32_16x16x32_bf16(qf[kk].b, kf.b, s[c], 0, 0, 0);
      }
    }
    __builtin_amdgcn_s_setprio(0);

    // scale + rel bias
#pragma unroll
    for (int c = 0; c < 4; ++c) {
      const u16* rc = (const u16*)&rl[c];
#pragma unroll
      for (int j = 0; j < 4; ++j) s[c][j] = s[c][j] * 0.125f + bf2f(rc[j]);
    }
    // online softmax (rows live across the 16 lanes sharing g)
    float fac[4];
#pragma unroll
    for (int j = 0; j < 4; ++j) {
      float pm = fmaxf(fmaxf(s[0][j], s[1][j]), fmaxf(s[2][j], s[3][j]));
      pm = fmaxf(pm, __shfl_xor(pm, 1));
      pm = fmaxf(pm, __shfl_xor(pm, 2));
      pm = fmaxf(pm, __shfl_xor(pm, 4));
      pm = fmaxf(pm, __shfl_xor(pm, 8));
      float mnew = fmaxf(m_run[j], pm);
      fac[j] = __expf(m_run[j] - mnew);
      m_run[j] = mnew;
    }
#pragma unroll
    for (int c = 0; c < 4; ++c)
#pragma unroll
      for (int j = 0; j < 4; ++j) s[c][j] = __expf(s[c][j] - m_run[j]);
#pragma unroll
    for (int j = 0; j < 4; ++j) {
      float rs = s[0][j] + s[1][j] + s[2][j] + s[3][j];
      rs += __shfl_xor(rs, 1);
      rs += __shfl_xor(rs, 2);
      rs += __shfl_xor(rs, 4);
      rs += __shfl_xor(rs, 8);
      l_run[j] = l_run[j] * fac[j] + rs;
    }
#pragma unroll
    for (int c = 0; c < 4; ++c)
#pragma unroll
      for (int j = 0; j < 4; ++j) acc[c][j] *= fac[j];

    // write P (bf16) to per-wave LDS region (wave-private; lgkmcnt orders it)
    u16* Pw = Pl[wid];
#pragma unroll
    for (int c = 0; c < 4; ++c)
#pragma unroll
      for (int j = 0; j < 4; ++j)
        Pw[(4 * g + j) * 68 + c * 16 + i16] = f2bf(s[c][j]);

    // O += P V
    U8 pf[2];
#pragma unroll
    for (int kk = 0; kk < 2; ++kk) {
      const u16* p = Pl[wid] + i16 * 68 + 8 * g + 32 * kk;
      pf[kk].u2[0] = *(const uint2*)p;
      pf[kk].u2[1] = *(const uint2*)(p + 4);
    }
    __builtin_amdgcn_s_setprio(1);
#pragma unroll
    for (int c = 0; c < 4; ++c) {
#pragma unroll
      for (int kk = 0; kk < 2; ++kk) {
        int row = c * 16 + i16;
        int ch = (g + 4 * kk) ^ (row & 7);
        U8 vf;
        vf.u4 = *(const uint4*)(&Vl[buf][row * 64 + ch * 8]);
        acc[c] = __builtin_amdgcn_mfma_f32_16x16x32_bf16(pf[kk].b, vf.b, acc[c], 0, 0, 0);
      }
    }
    __builtin_amdgcn_s_setprio(0);
    __syncthreads();  // end-of-tile: drains prefetch; protects buf reuse
  }
#undef STAGE

  // epilogue: normalize, write bf16 [b][n][h*64+d]
#pragma unroll
  for (int c = 0; c < 4; ++c) {
#pragma unroll
    for (int j = 0; j < 4; ++j) {
      int n = qt * 64 + wid * 16 + 4 * g + j;
      float v = acc[c][j] / l_run[j];
      Out[((size_t)b * 512 + n) * 1024 + h * 64 + c * 16 + i16] = f2bf(v);
    }
  }
}

// ---------------- launcher ----------------
extern "C" void kernel_launch(void* const* d_in, const int* in_sizes, int n_in,
                              void* d_out, int out_size, void* d_ws, size_t ws_size,
                              hipStream_t stream) {
  const float* x = (const float*)d_in[0];
  const float* rel_bias = (const float*)d_in[1];
  const float* W_qkv = (const float*)d_in[2];
  const float* b_qkv = (const float*)d_in[3];
  const float* W_rel = (const float*)d_in[4];
  const float* b_rel = (const float*)d_in[5];
  const float* W_out = (const float*)d_in[6];
  const float* b_out = (const float*)d_in[7];
  float* out = (float*)d_out;

  char* ws = (char*)d_ws;
  u16* x_bf    = (u16*)(ws);               //  8 MB  (4096x1024)
  u16* wqkv_bf = (u16*)(ws + 8388608);     //  6 MB  (3072x1024)
  u16* wout_bf = (u16*)(ws + 14680064);    //  2 MB  (1024x1024)
  u16* Qw      = (u16*)(ws + 16777216);    //  8 MB  [b][h][n][d]
  u16* Kw      = (u16*)(ws + 25165824);    //  8 MB  [b][h][n][d]
  u16* Vt      = (u16*)(ws + 33554432);    //  8 MB  [b][h][d][n] (written by qkv gemm)
  u16* relb    = (u16*)(ws + 41943040);    // 64 MB  fragment-ordered rel
  u16* attno   = (u16*)(ws + 109051904);   //  8 MB  (4096x1024)

  k_convert_all<<<2048, 256, 0, stream>>>(x, W_qkv, W_out, x_bf, wqkv_bf, wout_bf);

  k_rel<<<dim3(8, 128, 8), 256, 0, stream>>>(rel_bias, W_rel, b_rel, relb);

  k_gemm_qkv<<<dim3(24, 32), 256, 0, stream>>>(x_bf, wqkv_bf, b_qkv, Qw, Kw, Vt);

  k_attn<<<dim3(8, 16, 8), 256, 0, stream>>>(Qw, Kw, Vt, relb, attno);

  k_gemm_out<<<dim3(8, 32), 256, 0, stream>>>(attno, wout_bf, b_out, out);
}